// Round 2
// baseline (685.650 us; speedup 1.0000x reference)
//
#include <hip/hip_runtime.h>
#include <stdint.h>

// GraphAttention on MI355X — ALL I/O float32 (per reference dtypes).
// Inputs: X[8192][128], A[8192][8192] (0/1), W[4][128][64], a_self[4][64],
// a_neigh[4][64].  Output f32 [8192][256].
//
// dense[h,n,m] = leakyrelu_0.2(s_self[h,n] + s_neigh[h,m]); softmax over m with
// A==0 -> weight exactly 0; out = relu(attn @ Xp), heads concat.
//
// K0 W->WT bf16 -> K1 MFMA projection (X cast bf16 in LDS) + scores ->
// K1b per-head global max bound M[h] (single-pass softmax) ->
// K2 fused mask/exp/softmax-numerator + P·V MFMA, head-per-wave, m-split=4 ->
// K3 combine/divide/relu.

#define NN    8192
#define FF    128
#define FD    64
#define HH    4
#define SPLIT 4
#define KT_PER_SPLIT ((NN / SPLIT) / 32)   // 64 k-tiles of 32 columns per split
#define LOG2E 1.4426950408889634f

typedef __attribute__((ext_vector_type(8))) short short8;
typedef __attribute__((ext_vector_type(4))) float f32x4;

extern "C" __device__ float __ocml_exp2_f32(float);

__device__ __forceinline__ float fast_exp2(float x) {
#if __has_builtin(__builtin_amdgcn_exp2f)
    return __builtin_amdgcn_exp2f(x);
#else
    return __ocml_exp2_f32(x);
#endif
}

__device__ __forceinline__ float bf16_to_f32(unsigned short u) {
    return __builtin_bit_cast(float, ((unsigned)u) << 16);
}
__device__ __forceinline__ unsigned f32_to_bf16_rne(float f) {
    unsigned u = __builtin_bit_cast(unsigned, f);
    u = (u + 0x7FFFu + ((u >> 16) & 1u)) >> 16;
    return u;
}
// Pack two f32 -> two bf16 (truncation) in ONE v_perm_b32.  lo -> bits[15:0].
__device__ __forceinline__ unsigned pack_bf16_trunc(float lo, float hi) {
    return __builtin_amdgcn_perm(__builtin_bit_cast(unsigned, hi),
                                 __builtin_bit_cast(unsigned, lo), 0x07060302u);
}

// ---------------- workspace layout (bytes), ~21 MiB ----------------
#define WS_XPT   0                                   // bf16 [H][64][N]   (Xp^T per head)
#define WS_U     (WS_XPT + HH * FD * NN * 2)         // f32  [H][N]  raw s_self
#define WS_V     (WS_U + HH * NN * 4)                // f32  [H][N]  raw s_neigh
#define WS_VC    (WS_V + HH * NN * 4)                // f32  [H][N]  s_neigh * log2e
#define WS_M     (WS_VC + HH * NN * 4)               // f32  [H] (padded to 256B)
#define WS_WT    (WS_M + 256)                        // bf16 [H][64][128] (W^T per head)
#define WS_ACCP  (WS_WT + HH * FD * FF * 2)          // bf16 [SPLIT][H][N][64]
#define WS_LP    (WS_ACCP + (size_t)SPLIT * HH * NN * FD * 2)  // f32 [SPLIT][H][N]

// ---------------- K0: W[h][f][d] f32 -> WT[h][d][f] bf16 ----------------
__global__ void k0_transpose_w(const float* __restrict__ W,
                               unsigned short* __restrict__ WT) {
    int b = blockIdx.x;            // 32 blocks
    int h = b >> 3, fb = b & 7;
    int t = threadIdx.x;
    int d = t & 63, fo = t >> 6;
    #pragma unroll
    for (int i = 0; i < 4; ++i) {
        int f = fb * 16 + fo * 4 + i;
        WT[(h * FD + d) * FF + f] = (unsigned short)f32_to_bf16_rne(W[(h * FF + f) * FD + d]);
    }
}

// ---------------- K1: Xp = X @ W[h] via bf16 MFMA; scores; XpT bf16 ----------------
__global__ __launch_bounds__(256) void k1_project(
        const float* __restrict__ X,               // [N][128] f32
        const unsigned short* __restrict__ WT,     // [H][64][128] bf16
        const float* __restrict__ a_self,          // [H][64] f32
        const float* __restrict__ a_neigh,
        unsigned short* __restrict__ XpT,          // [H][64][N] bf16
        float* __restrict__ U, float* __restrict__ V) {
    // 64 X-rows per block, one head.  272B LDS row stride (bf16 rows of 256B + 16B pad).
    __shared__ __align__(16) char XsB[64 * 272];
    __shared__ __align__(16) char WsB[64 * 272];
    const int rb = blockIdx.x * 64;
    const int h  = blockIdx.y;
    const int t  = threadIdx.x;
    // X tile: 64x128 f32 = 2048 float4; convert to bf16 on the way into LDS
    const float4* xs = (const float4*)(X + (size_t)rb * FF);
    #pragma unroll
    for (int i = 0; i < 8; ++i) {
        int c = i * 256 + t;
        float4 v = xs[c];
        uint2 pv;
        pv.x = f32_to_bf16_rne(v.x) | (f32_to_bf16_rne(v.y) << 16);
        pv.y = f32_to_bf16_rne(v.z) | (f32_to_bf16_rne(v.w) << 16);
        *(uint2*)(XsB + (c >> 5) * 272 + (c & 31) * 8) = pv;
    }
    const uint4* wsrc = (const uint4*)(WT + (size_t)h * FD * FF);  // 16KB bf16
    #pragma unroll
    for (int i = 0; i < 4; ++i) {
        int c = i * 256 + t;
        *(uint4*)(WsB + (c >> 4) * 272 + (c & 15) * 16) = wsrc[c];
    }
    __syncthreads();
    const int lane = t & 63, wid = t >> 6;
    const int r15 = lane & 15, quad = lane >> 4;
    const int lrow = wid * 16 + r15;

    f32x4 acc[4];
    #pragma unroll
    for (int cg = 0; cg < 4; ++cg) acc[cg] = (f32x4){0.f, 0.f, 0.f, 0.f};
    #pragma unroll
    for (int kt = 0; kt < 4; ++kt) {
        short8 afr = *(const short8*)(XsB + lrow * 272 + kt * 64 + quad * 16);
        #pragma unroll
        for (int cg = 0; cg < 4; ++cg) {
            short8 bfr = *(const short8*)(WsB + (cg * 16 + r15) * 272 + kt * 64 + quad * 16);
            acc[cg] = __builtin_amdgcn_mfma_f32_16x16x32_bf16(afr, bfr, acc[cg], 0, 0, 0);
        }
    }
    // scores: s = Xp . a  (C layout: col = r15, row = quad*4+reg)
    float as[4], an[4];
    #pragma unroll
    for (int cg = 0; cg < 4; ++cg) {
        as[cg] = a_self[h * FD + cg * 16 + r15];
        an[cg] = a_neigh[h * FD + cg * 16 + r15];
    }
    #pragma unroll
    for (int reg = 0; reg < 4; ++reg) {
        float s1 = 0.f, s2 = 0.f;
        #pragma unroll
        for (int cg = 0; cg < 4; ++cg) { s1 += acc[cg][reg] * as[cg]; s2 += acc[cg][reg] * an[cg]; }
        #pragma unroll
        for (int m = 1; m <= 8; m <<= 1) { s1 += __shfl_xor(s1, m); s2 += __shfl_xor(s2, m); }
        if (r15 == 0) {
            int n = rb + wid * 16 + quad * 4 + reg;
            U[h * NN + n] = s1;
            V[h * NN + n] = s2;
        }
    }
    // XpT[h][d][n] bf16; 4 consecutive n per cg -> 8B store
    #pragma unroll
    for (int cg = 0; cg < 4; ++cg) {
        uint2 val;
        val.x = f32_to_bf16_rne(acc[cg][0]) | (f32_to_bf16_rne(acc[cg][1]) << 16);
        val.y = f32_to_bf16_rne(acc[cg][2]) | (f32_to_bf16_rne(acc[cg][3]) << 16);
        int d = cg * 16 + r15;
        int n0 = rb + wid * 16 + quad * 4;
        *(uint2*)((char*)XpT + ((size_t)(h * FD + d) * NN + n0) * 2) = val;
    }
}

// ---------------- K1b: per-head max bound M[h], Vc = V * log2e ----------------
__global__ void k1b_max(const float* __restrict__ U, const float* __restrict__ V,
                        float* __restrict__ Vc, float* __restrict__ M) {
    int h = blockIdx.x, t = threadIdx.x;
    __shared__ float red[256];
    float mu = -1e30f, mv = -1e30f;
    for (int i = t; i < NN; i += 256) {
        mu = fmaxf(mu, U[h * NN + i]);
        mv = fmaxf(mv, V[h * NN + i]);
    }
    red[t] = mu; __syncthreads();
    for (int s = 128; s > 0; s >>= 1) { if (t < s) red[t] = fmaxf(red[t], red[t + s]); __syncthreads(); }
    float Mu = red[0]; __syncthreads();
    red[t] = mv; __syncthreads();
    for (int s = 128; s > 0; s >>= 1) { if (t < s) red[t] = fmaxf(red[t], red[t + s]); __syncthreads(); }
    float Mv = red[0];
    if (t == 0) M[h] = Mu + Mv;
    for (int i = t; i < NN; i += 256) Vc[h * NN + i] = V[h * NN + i] * LOG2E;
}

// ---------------- K2: fused scores/softmax-numerator + P.V MFMA ----------------
// block = 4 waves = 64 rows; wave w owns head w; grid (128 row-blocks, SPLIT m-splits).
__global__ __launch_bounds__(256, 2) void k2_attend(
        const float* __restrict__ Ag,              // [N][N] f32 0/1
        const unsigned short* __restrict__ XpT,    // [H][64][N] bf16
        const float* __restrict__ U, const float* __restrict__ Vc,
        const float* __restrict__ Mbuf,
        unsigned short* __restrict__ accP,         // [SPLIT][H][N][64] bf16
        float* __restrict__ lP) {                  // f32 [SPLIT][H][N]
    __shared__ __align__(16) char Xsb[HH * FD * 80];  // 256 rows: 64B data + 16B pad
    __shared__ float Vs[HH * 32];
    const int t = threadIdx.x;
    const int lane = t & 63, wid = t >> 6;
    const int r15 = lane & 15, quad = lane >> 4;
    const int rb = blockIdx.x * 64;
    const int sp = blockIdx.y;
    const int h = wid;                             // head-per-wave

    const float mh = Mbuf[h];
    const float qoff = -0.8f * mh * LOG2E;         // q = 0.2*p + qoff == (0.2 s - M)*log2e
    float u1g[4];
    #pragma unroll
    for (int g = 0; g < 4; ++g)
        u1g[g] = (U[h * NN + rb + g * 16 + r15] - mh) * LOG2E;

    f32x4 acc[4][4];
    #pragma unroll
    for (int g = 0; g < 4; ++g)
        #pragma unroll
        for (int cg = 0; cg < 4; ++cg) acc[g][cg] = (f32x4){0.f, 0.f, 0.f, 0.f};
    float lsum[4] = {0.f, 0.f, 0.f, 0.f};

    const int kb0 = sp * (NN / SPLIT);
    float4 abuf[2][8];                             // A rows rb+g*16+r15, 32 cols
    uint4  cbuf[2][4];                             // XpT staging row t, 32 bf16
    float  vbuf[2];
    {
        #pragma unroll
        for (int g = 0; g < 4; ++g) {
            const float* arow = Ag + (size_t)(rb + g * 16 + r15) * NN + kb0 + quad * 8;
            abuf[0][g * 2]     = *(const float4*)(arow);
            abuf[0][g * 2 + 1] = *(const float4*)(arow + 4);
        }
        const uint4* src = (const uint4*)((const char*)XpT + ((size_t)t * NN + kb0) * 2);
        cbuf[0][0] = src[0]; cbuf[0][1] = src[1]; cbuf[0][2] = src[2]; cbuf[0][3] = src[3];
        vbuf[0] = (t < 128) ? Vc[(t >> 5) * NN + kb0 + (t & 31)] : 0.f;
    }

    #pragma unroll 2
    for (int kt = 0; kt < KT_PER_SPLIT; ++kt) {
        const int cur = kt & 1, nxt = cur ^ 1;
        __syncthreads();                           // previous tile's LDS reads done
        #pragma unroll
        for (int i = 0; i < 4; ++i)
            *(uint4*)(Xsb + t * 80 + i * 16) = cbuf[cur][i];
        if (t < 128) Vs[t] = vbuf[cur];
        __syncthreads();

        {   // prefetch next tile (clamped duplicate on last iteration — discarded)
            const int kbn = kb0 + ((kt + 1 < KT_PER_SPLIT) ? (kt + 1) * 32 : kt * 32);
            #pragma unroll
            for (int g = 0; g < 4; ++g) {
                const float* arow = Ag + (size_t)(rb + g * 16 + r15) * NN + kbn + quad * 8;
                abuf[nxt][g * 2]     = *(const float4*)(arow);
                abuf[nxt][g * 2 + 1] = *(const float4*)(arow + 4);
            }
            const uint4* src = (const uint4*)((const char*)XpT + ((size_t)t * NN + kbn) * 2);
            cbuf[nxt][0] = src[0]; cbuf[nxt][1] = src[1];
            cbuf[nxt][2] = src[2]; cbuf[nxt][3] = src[3];
            vbuf[nxt] = (t < 128) ? Vc[(t >> 5) * NN + kbn + (t & 31)] : 0.f;
        }

        short8 bfr[4];                             // head h's B-frags, shared across g
        #pragma unroll
        for (int cg = 0; cg < 4; ++cg)
            bfr[cg] = *(const short8*)(Xsb + (h * FD + cg * 16 + r15) * 80 + quad * 16);
        f32x4 va  = *(const f32x4*)(&Vs[h * 32 + quad * 8]);
        f32x4 vb2 = *(const f32x4*)(&Vs[h * 32 + quad * 8 + 4]);

        #pragma unroll
        for (int g = 0; g < 4; ++g) {
            float w[8];
            #pragma unroll
            for (int j = 0; j < 4; ++j) {
                float p = u1g[g] + va[j];
                float q = fmaf(0.2f, p, qoff);
                w[j] = fast_exp2(fmaxf(p, q)) * abuf[cur][g * 2][j];     // exp(leaky-M)*mask
            }
            #pragma unroll
            for (int j = 0; j < 4; ++j) {
                float p = u1g[g] + vb2[j];
                float q = fmaf(0.2f, p, qoff);
                w[4 + j] = fast_exp2(fmaxf(p, q)) * abuf[cur][g * 2 + 1][j];
            }
            lsum[g] += ((w[0] + w[1]) + (w[2] + w[3])) + ((w[4] + w[5]) + (w[6] + w[7]));
            uint4 pkv;
            pkv.x = pack_bf16_trunc(w[0], w[1]);
            pkv.y = pack_bf16_trunc(w[2], w[3]);
            pkv.z = pack_bf16_trunc(w[4], w[5]);
            pkv.w = pack_bf16_trunc(w[6], w[7]);
            short8 afrag = __builtin_bit_cast(short8, pkv);
            #pragma unroll
            for (int cg = 0; cg < 4; ++cg)
                acc[g][cg] = __builtin_amdgcn_mfma_f32_16x16x32_bf16(afrag, bfr[cg], acc[g][cg], 0, 0, 0);
        }
    }
    // row denominators: combine the 4 quad-lanes sharing each row
    #pragma unroll
    for (int g = 0; g < 4; ++g) {
        lsum[g] += __shfl_xor(lsum[g], 16);
        lsum[g] += __shfl_xor(lsum[g], 32);
    }
    if (lane < 16) {
        #pragma unroll
        for (int g = 0; g < 4; ++g)
            lP[(size_t)(sp * HH + h) * NN + rb + g * 16 + lane] = lsum[g];
    }
    #pragma unroll
    for (int g = 0; g < 4; ++g)
        #pragma unroll
        for (int cg = 0; cg < 4; ++cg) {
            int d = cg * 16 + r15;
            #pragma unroll
            for (int reg = 0; reg < 4; ++reg) {
                int n = rb + g * 16 + quad * 4 + reg;
                accP[((size_t)(sp * HH + h) * NN + n) * FD + d] =
                    (unsigned short)f32_to_bf16_rne(acc[g][cg][reg]);
            }
        }
}

// ---------------- K3: combine splits, divide, relu, concat ----------------
__global__ void k3_combine(const unsigned short* __restrict__ accP,
                           const float* __restrict__ lP,
                           float* __restrict__ out) {
    int e = blockIdx.x * 256 + threadIdx.x;     // 2M elements: out[n][h*64+d]
    int n = e >> 8, c = e & 255;
    int h = c >> 6, d = c & 63;
    float num = 0.f, den = 0.f;
    #pragma unroll
    for (int s = 0; s < SPLIT; ++s) {
        num += bf16_to_f32(accP[((size_t)(s * HH + h) * NN + n) * FD + d]);
        den += lP[(size_t)(s * HH + h) * NN + n];
    }
    out[e] = fmaxf(num * __builtin_amdgcn_rcpf(den), 0.f);
}

extern "C" void kernel_launch(void* const* d_in, const int* in_sizes, int n_in,
                              void* d_out, int out_size, void* d_ws, size_t ws_size,
                              hipStream_t stream) {
    (void)in_sizes; (void)n_in; (void)out_size; (void)ws_size;
    const float* X       = (const float*)d_in[0];
    const float* A       = (const float*)d_in[1];
    const float* W       = (const float*)d_in[2];
    const float* a_self  = (const float*)d_in[3];
    const float* a_neigh = (const float*)d_in[4];
    char* ws = (char*)d_ws;
    unsigned short* XpT  = (unsigned short*)(ws + WS_XPT);
    float*          U    = (float*)(ws + WS_U);
    float*          V    = (float*)(ws + WS_V);
    float*          Vc   = (float*)(ws + WS_VC);
    float*          M    = (float*)(ws + WS_M);
    unsigned short* WT   = (unsigned short*)(ws + WS_WT);
    unsigned short* accP = (unsigned short*)(ws + WS_ACCP);
    float*          lP   = (float*)(ws + WS_LP);
    float*          out  = (float*)d_out;

    k0_transpose_w<<<dim3(32), dim3(256), 0, stream>>>(W, WT);
    k1_project<<<dim3(NN / 64, HH), dim3(256), 0, stream>>>(X, WT, a_self, a_neigh, XpT, U, V);
    k1b_max<<<dim3(HH), dim3(256), 0, stream>>>(U, V, Vc, M);
    k2_attend<<<dim3(NN / 64, SPLIT), dim3(256), 0, stream>>>(A, XpT, U, Vc, M, accP, lP);
    k3_combine<<<dim3(NN), dim3(256), 0, stream>>>(accP, lP, out);
}

// Round 3
// 538.350 us; speedup vs baseline: 1.2736x; 1.2736x over previous
//
#include <hip/hip_runtime.h>
#include <stdint.h>

// GraphAttention on MI355X — ALL I/O float32.
// X[8192][128], A[8192][8192] (0/1), W[4][128][64], a_self[4][64], a_neigh[4][64]
// -> out f32 [8192][256].
//
// K0 W->WT bf16 -> K1 MFMA projection + scores -> K1b per-head bound M[h]
// (single-pass softmax) -> K2 fused mask/exp/softmax-num + P.V MFMA
// (global_load_lds double-buffered XpT staging, head-per-wave, m-split=8)
// -> K3 combine/divide/relu.

#define NN    8192
#define FF    128
#define FD    64
#define HH    4
#define SPLIT 8
#define KT_PER_SPLIT ((NN / SPLIT) / 32)   // 32 k-tiles of 32 columns per split
#define LOG2E 1.4426950408889634f

typedef __attribute__((ext_vector_type(8))) short short8;
typedef __attribute__((ext_vector_type(4))) float f32x4;

extern "C" __device__ float __ocml_exp2_f32(float);

__device__ __forceinline__ float fast_exp2(float x) {
#if __has_builtin(__builtin_amdgcn_exp2f)
    return __builtin_amdgcn_exp2f(x);
#else
    return __ocml_exp2_f32(x);
#endif
}

__device__ __forceinline__ float bf16_to_f32(unsigned short u) {
    return __builtin_bit_cast(float, ((unsigned)u) << 16);
}
__device__ __forceinline__ unsigned f32_to_bf16_rne(float f) {
    unsigned u = __builtin_bit_cast(unsigned, f);
    u = (u + 0x7FFFu + ((u >> 16) & 1u)) >> 16;
    return u;
}
// Pack two f32 -> two bf16 (truncation) in ONE v_perm_b32.  lo -> bits[15:0].
__device__ __forceinline__ unsigned pack_bf16_trunc(float lo, float hi) {
    return __builtin_amdgcn_perm(__builtin_bit_cast(unsigned, hi),
                                 __builtin_bit_cast(unsigned, lo), 0x07060302u);
}
// async global->LDS DMA, 16B per lane; LDS dest = ldsbase + lane*16.
__device__ __forceinline__ void async_load16(const void* g, void* l) {
    __builtin_amdgcn_global_load_lds(
        (const __attribute__((address_space(1))) unsigned int*)g,
        (__attribute__((address_space(3))) unsigned int*)l, 16, 0, 0);
}

// ---------------- workspace layout (bytes), ~39 MiB ----------------
#define WS_XPT   0                                   // bf16 [H][64][N]   (Xp^T per head)
#define WS_U     (WS_XPT + HH * FD * NN * 2)         // f32  [H][N]  raw s_self
#define WS_V     (WS_U + HH * NN * 4)                // f32  [H][N]  raw s_neigh
#define WS_VC    (WS_V + HH * NN * 4)                // f32  [H][N]  s_neigh * log2e
#define WS_M     (WS_VC + HH * NN * 4)               // f32  [H] (padded to 256B)
#define WS_WT    (WS_M + 256)                        // bf16 [H][64][128] (W^T per head)
#define WS_ACCP  (WS_WT + HH * FD * FF * 2)          // bf16 [SPLIT][H][N][64]
#define WS_LP    (WS_ACCP + (size_t)SPLIT * HH * NN * FD * 2)  // f32 [SPLIT][H][N]

// ---------------- K0: W[h][f][d] f32 -> WT[h][d][f] bf16 ----------------
__global__ void k0_transpose_w(const float* __restrict__ W,
                               unsigned short* __restrict__ WT) {
    int b = blockIdx.x;            // 32 blocks
    int h = b >> 3, fb = b & 7;
    int t = threadIdx.x;
    int d = t & 63, fo = t >> 6;
    #pragma unroll
    for (int i = 0; i < 4; ++i) {
        int f = fb * 16 + fo * 4 + i;
        WT[(h * FD + d) * FF + f] = (unsigned short)f32_to_bf16_rne(W[(h * FF + f) * FD + d]);
    }
}

// ---------------- K1: Xp = X @ W[h] via bf16 MFMA; scores; XpT bf16 ----------------
__global__ __launch_bounds__(256) void k1_project(
        const float* __restrict__ X,               // [N][128] f32
        const unsigned short* __restrict__ WT,     // [H][64][128] bf16
        const float* __restrict__ a_self,          // [H][64] f32
        const float* __restrict__ a_neigh,
        unsigned short* __restrict__ XpT,          // [H][64][N] bf16
        float* __restrict__ U, float* __restrict__ V) {
    __shared__ __align__(16) char XsB[64 * 272];
    __shared__ __align__(16) char WsB[64 * 272];
    const int rb = blockIdx.x * 64;
    const int h  = blockIdx.y;
    const int t  = threadIdx.x;
    const float4* xs = (const float4*)(X + (size_t)rb * FF);
    #pragma unroll
    for (int i = 0; i < 8; ++i) {
        int c = i * 256 + t;
        float4 v = xs[c];
        uint2 pv;
        pv.x = f32_to_bf16_rne(v.x) | (f32_to_bf16_rne(v.y) << 16);
        pv.y = f32_to_bf16_rne(v.z) | (f32_to_bf16_rne(v.w) << 16);
        *(uint2*)(XsB + (c >> 5) * 272 + (c & 31) * 8) = pv;
    }
    const uint4* wsrc = (const uint4*)(WT + (size_t)h * FD * FF);
    #pragma unroll
    for (int i = 0; i < 4; ++i) {
        int c = i * 256 + t;
        *(uint4*)(WsB + (c >> 4) * 272 + (c & 15) * 16) = wsrc[c];
    }
    __syncthreads();
    const int lane = t & 63, wid = t >> 6;
    const int r15 = lane & 15, quad = lane >> 4;
    const int lrow = wid * 16 + r15;

    f32x4 acc[4];
    #pragma unroll
    for (int cg = 0; cg < 4; ++cg) acc[cg] = (f32x4){0.f, 0.f, 0.f, 0.f};
    #pragma unroll
    for (int kt = 0; kt < 4; ++kt) {
        short8 afr = *(const short8*)(XsB + lrow * 272 + kt * 64 + quad * 16);
        #pragma unroll
        for (int cg = 0; cg < 4; ++cg) {
            short8 bfr = *(const short8*)(WsB + (cg * 16 + r15) * 272 + kt * 64 + quad * 16);
            acc[cg] = __builtin_amdgcn_mfma_f32_16x16x32_bf16(afr, bfr, acc[cg], 0, 0, 0);
        }
    }
    float as[4], an[4];
    #pragma unroll
    for (int cg = 0; cg < 4; ++cg) {
        as[cg] = a_self[h * FD + cg * 16 + r15];
        an[cg] = a_neigh[h * FD + cg * 16 + r15];
    }
    #pragma unroll
    for (int reg = 0; reg < 4; ++reg) {
        float s1 = 0.f, s2 = 0.f;
        #pragma unroll
        for (int cg = 0; cg < 4; ++cg) { s1 += acc[cg][reg] * as[cg]; s2 += acc[cg][reg] * an[cg]; }
        #pragma unroll
        for (int m = 1; m <= 8; m <<= 1) { s1 += __shfl_xor(s1, m); s2 += __shfl_xor(s2, m); }
        if (r15 == 0) {
            int n = rb + wid * 16 + quad * 4 + reg;
            U[h * NN + n] = s1;
            V[h * NN + n] = s2;
        }
    }
    #pragma unroll
    for (int cg = 0; cg < 4; ++cg) {
        uint2 val;
        val.x = f32_to_bf16_rne(acc[cg][0]) | (f32_to_bf16_rne(acc[cg][1]) << 16);
        val.y = f32_to_bf16_rne(acc[cg][2]) | (f32_to_bf16_rne(acc[cg][3]) << 16);
        int d = cg * 16 + r15;
        int n0 = rb + wid * 16 + quad * 4;
        *(uint2*)((char*)XpT + ((size_t)(h * FD + d) * NN + n0) * 2) = val;
    }
}

// ---------------- K1b: per-head max bound M[h], Vc = V * log2e ----------------
__global__ void k1b_max(const float* __restrict__ U, const float* __restrict__ V,
                        float* __restrict__ Vc, float* __restrict__ M) {
    int h = blockIdx.x, t = threadIdx.x;
    __shared__ float red[256];
    float mu = -1e30f, mv = -1e30f;
    for (int i = t; i < NN; i += 256) {
        mu = fmaxf(mu, U[h * NN + i]);
        mv = fmaxf(mv, V[h * NN + i]);
    }
    red[t] = mu; __syncthreads();
    for (int s = 128; s > 0; s >>= 1) { if (t < s) red[t] = fmaxf(red[t], red[t + s]); __syncthreads(); }
    float Mu = red[0]; __syncthreads();
    red[t] = mv; __syncthreads();
    for (int s = 128; s > 0; s >>= 1) { if (t < s) red[t] = fmaxf(red[t], red[t + s]); __syncthreads(); }
    float Mv = red[0];
    if (t == 0) M[h] = Mu + Mv;
    for (int i = t; i < NN; i += 256) Vc[h * NN + i] = V[h * NN + i] * LOG2E;
}

// ---------------- K2: fused scores/softmax-numerator + P.V MFMA ----------------
// 4 waves = 64 rows; wave w owns head w; grid (128 row-blocks, SPLIT m-splits).
// XpT tile staged via async global_load_lds, double-buffered, XOR-swizzled:
//   LDS(row, c') holds global chunk c = c' ^ ((row>>1)&3)   (16B chunks, 4/row)
__global__ __launch_bounds__(256, 3) void k2_attend(
        const float* __restrict__ Ag,              // [N][N] f32 0/1
        const unsigned short* __restrict__ XpT,    // [H][64][N] bf16
        const float* __restrict__ U, const float* __restrict__ Vc,
        const float* __restrict__ Mbuf,
        unsigned short* __restrict__ accP,         // [SPLIT][H][N][64] bf16
        float* __restrict__ lP) {                  // f32 [SPLIT][H][N]
    __shared__ __align__(16) char Xsb[2][16384];   // 2 x (256 rows x 64B)
    const int t = threadIdx.x;
    const int lane = t & 63, wid = t >> 6;
    const int r15 = lane & 15, quad = lane >> 4;
    const int rb = blockIdx.x * 64;
    const int sp = blockIdx.y;
    const int h = wid;                             // head-per-wave

    const float mh = Mbuf[h];
    const float qoff = -0.8f * mh * LOG2E;         // q = 0.2*p + qoff == (0.2 s - M)*log2e
    float u1g[4];
    #pragma unroll
    for (int g = 0; g < 4; ++g)
        u1g[g] = (U[h * NN + rb + g * 16 + r15] - mh) * LOG2E;

    f32x4 acc[4][4];
    #pragma unroll
    for (int g = 0; g < 4; ++g)
        #pragma unroll
        for (int cg = 0; cg < 4; ++cg) acc[g][cg] = (f32x4){0.f, 0.f, 0.f, 0.f};
    float lsum[4] = {0.f, 0.f, 0.f, 0.f};

    const int kb0 = sp * (NN / SPLIT);
    // staging source: instr i of wave w covers rows w*64+i*16+(lane>>2), lane chunk
    // c = (lane&3)^((lane>>3)&3)  (inverse of the LDS XOR swizzle, lane-constant)
    const int srow = wid * 64 + (lane >> 2);
    const int sc   = (lane & 3) ^ ((lane >> 3) & 3);
    const char* sbase = (const char*)XpT + ((size_t)srow * NN + kb0 + sc * 8) * 2;
    const size_t irow_step = (size_t)16 * NN * 2;  // 16 rows per instr
    // issue tile 0 into buffer 0
    #pragma unroll
    for (int i = 0; i < 4; ++i)
        async_load16(sbase + (size_t)i * irow_step, &Xsb[0][(wid * 4 + i) * 1024]);

    const float* aB = Ag + (size_t)rb * NN + kb0;  // A row-block base
    const int swz = (quad ^ ((r15 >> 1) & 3)) * 16;

    #pragma unroll 2
    for (int kt = 0; kt < KT_PER_SPLIT; ++kt) {
        const int cur = kt & 1;
        __syncthreads();                           // drains tile kt DMA; buf[cur^1] free
        if (kt + 1 < KT_PER_SPLIT) {               // prefetch tile kt+1
            const char* sb2 = sbase + (size_t)(kt + 1) * 64;
            #pragma unroll
            for (int i = 0; i < 4; ++i)
                async_load16(sb2 + (size_t)i * irow_step, &Xsb[cur ^ 1][(wid * 4 + i) * 1024]);
        }
        const int kb = kt * 32;
        // A tile loads: 8 independent float4 (32B contiguous per lane)
        float4 a0[4], a1[4];
        #pragma unroll
        for (int g = 0; g < 4; ++g) {
            const float* ar = aB + (size_t)(g * 16 + r15) * NN + kb + quad * 8;
            a0[g] = *(const float4*)(ar);
            a1[g] = *(const float4*)(ar + 4);
        }
        const float* vr = Vc + h * NN + kb0 + kb + quad * 8;
        float4 va  = *(const float4*)(vr);
        float4 vb2 = *(const float4*)(vr + 4);
        // B-frags for head h (shared across g): swizzled ds_read_b128 x4
        short8 bfr[4];
        #pragma unroll
        for (int cg = 0; cg < 4; ++cg)
            bfr[cg] = *(const short8*)(&Xsb[cur][(h * FD + cg * 16 + r15) * 64 + swz]);

        #pragma unroll
        for (int g = 0; g < 4; ++g) {
            float w[8];
            #pragma unroll
            for (int j = 0; j < 4; ++j) {
                float p = u1g[g] + ((const float*)&va)[j];
                float q = fmaf(0.2f, p, qoff);
                w[j] = fast_exp2(fmaxf(p, q)) * ((const float*)&a0[g])[j];
            }
            #pragma unroll
            for (int j = 0; j < 4; ++j) {
                float p = u1g[g] + ((const float*)&vb2)[j];
                float q = fmaf(0.2f, p, qoff);
                w[4 + j] = fast_exp2(fmaxf(p, q)) * ((const float*)&a1[g])[j];
            }
            lsum[g] += ((w[0] + w[1]) + (w[2] + w[3])) + ((w[4] + w[5]) + (w[6] + w[7]));
            uint4 pkv;
            pkv.x = pack_bf16_trunc(w[0], w[1]);
            pkv.y = pack_bf16_trunc(w[2], w[3]);
            pkv.z = pack_bf16_trunc(w[4], w[5]);
            pkv.w = pack_bf16_trunc(w[6], w[7]);
            short8 afrag = __builtin_bit_cast(short8, pkv);
            #pragma unroll
            for (int cg = 0; cg < 4; ++cg)
                acc[g][cg] = __builtin_amdgcn_mfma_f32_16x16x32_bf16(afrag, bfr[cg], acc[g][cg], 0, 0, 0);
        }
    }
    // row denominators: combine the 4 quad-lanes sharing each row
    #pragma unroll
    for (int g = 0; g < 4; ++g) {
        lsum[g] += __shfl_xor(lsum[g], 16);
        lsum[g] += __shfl_xor(lsum[g], 32);
    }
    if (lane < 16) {
        #pragma unroll
        for (int g = 0; g < 4; ++g)
            lP[(size_t)(sp * HH + h) * NN + rb + g * 16 + lane] = lsum[g];
    }
    #pragma unroll
    for (int g = 0; g < 4; ++g)
        #pragma unroll
        for (int cg = 0; cg < 4; ++cg) {
            int d = cg * 16 + r15;
            #pragma unroll
            for (int reg = 0; reg < 4; ++reg) {
                int n = rb + g * 16 + quad * 4 + reg;
                accP[((size_t)(sp * HH + h) * NN + n) * FD + d] =
                    (unsigned short)f32_to_bf16_rne(acc[g][cg][reg]);
            }
        }
}

// ---------------- K3: combine splits, divide, relu, concat ----------------
__global__ void k3_combine(const unsigned short* __restrict__ accP,
                           const float* __restrict__ lP,
                           float* __restrict__ out) {
    int e = blockIdx.x * 256 + threadIdx.x;     // 2M elements: out[n][h*64+d]
    int n = e >> 8, c = e & 255;
    int h = c >> 6, d = c & 63;
    float num = 0.f, den = 0.f;
    #pragma unroll
    for (int s = 0; s < SPLIT; ++s) {
        num += bf16_to_f32(accP[((size_t)(s * HH + h) * NN + n) * FD + d]);
        den += lP[(size_t)(s * HH + h) * NN + n];
    }
    out[e] = fmaxf(num * __builtin_amdgcn_rcpf(den), 0.f);
}

extern "C" void kernel_launch(void* const* d_in, const int* in_sizes, int n_in,
                              void* d_out, int out_size, void* d_ws, size_t ws_size,
                              hipStream_t stream) {
    (void)in_sizes; (void)n_in; (void)out_size; (void)ws_size;
    const float* X       = (const float*)d_in[0];
    const float* A       = (const float*)d_in[1];
    const float* W       = (const float*)d_in[2];
    const float* a_self  = (const float*)d_in[3];
    const float* a_neigh = (const float*)d_in[4];
    char* ws = (char*)d_ws;
    unsigned short* XpT  = (unsigned short*)(ws + WS_XPT);
    float*          U    = (float*)(ws + WS_U);
    float*          V    = (float*)(ws + WS_V);
    float*          Vc   = (float*)(ws + WS_VC);
    float*          M    = (float*)(ws + WS_M);
    unsigned short* WT   = (unsigned short*)(ws + WS_WT);
    unsigned short* accP = (unsigned short*)(ws + WS_ACCP);
    float*          lP   = (float*)(ws + WS_LP);
    float*          out  = (float*)d_out;

    k0_transpose_w<<<dim3(32), dim3(256), 0, stream>>>(W, WT);
    k1_project<<<dim3(NN / 64, HH), dim3(256), 0, stream>>>(X, WT, a_self, a_neigh, XpT, U, V);
    k1b_max<<<dim3(HH), dim3(256), 0, stream>>>(U, V, Vc, M);
    k2_attend<<<dim3(NN / 64, SPLIT), dim3(256), 0, stream>>>(A, XpT, U, Vc, M, accP, lP);
    k3_combine<<<dim3(NN), dim3(256), 0, stream>>>(accP, lP, out);
}

// Round 4
// 506.162 us; speedup vs baseline: 1.3546x; 1.0636x over previous
//
#include <hip/hip_runtime.h>
#include <stdint.h>

// GraphAttention on MI355X — ALL I/O float32.
// X[8192][128], A[8192][8192] (0/1), W[4][128][64], a_self[4][64], a_neigh[4][64]
// -> out f32 [8192][256].
//
// K0 W->WT bf16 + zero max-keys -> K1 MFMA projection + scores + atomicMax head
// bounds -> K2 fused mask/exp/softmax-num + P.V MFMA (ALL global traffic staged
// via global_load_lds double-buffer, m97-style; head-per-wave; m-split=8)
// -> K3 combine/divide/relu.

#define NN    8192
#define FF    128
#define FD    64
#define HH    4
#define SPLIT 8
#define KT_PER_SPLIT ((NN / SPLIT) / 32)   // 32 k-tiles of 32 columns per split
#define LOG2E 1.4426950408889634f

typedef __attribute__((ext_vector_type(8))) short short8;
typedef __attribute__((ext_vector_type(4))) float f32x4;

extern "C" __device__ float __ocml_exp2_f32(float);

__device__ __forceinline__ float fast_exp2(float x) {
#if __has_builtin(__builtin_amdgcn_exp2f)
    return __builtin_amdgcn_exp2f(x);
#else
    return __ocml_exp2_f32(x);
#endif
}

__device__ __forceinline__ float bf16_to_f32(unsigned short u) {
    return __builtin_bit_cast(float, ((unsigned)u) << 16);
}
__device__ __forceinline__ unsigned f32_to_bf16_rne(float f) {
    unsigned u = __builtin_bit_cast(unsigned, f);
    u = (u + 0x7FFFu + ((u >> 16) & 1u)) >> 16;
    return u;
}
// Pack two f32 -> two bf16 (truncation) in ONE v_perm_b32.  lo -> bits[15:0].
__device__ __forceinline__ unsigned pack_bf16_trunc(float lo, float hi) {
    return __builtin_amdgcn_perm(__builtin_bit_cast(unsigned, hi),
                                 __builtin_bit_cast(unsigned, lo), 0x07060302u);
}
// async global->LDS DMA, 16B per lane; LDS dest = ldsbase + lane*16.
__device__ __forceinline__ void async_load16(const void* g, void* l) {
    __builtin_amdgcn_global_load_lds(
        (const __attribute__((address_space(1))) unsigned int*)g,
        (__attribute__((address_space(3))) unsigned int*)l, 16, 0, 0);
}
// order-preserving float<->uint keys for atomicMax over signed floats
__device__ __forceinline__ unsigned enc_key(float f) {
    unsigned u = __builtin_bit_cast(unsigned, f);
    return (u & 0x80000000u) ? ~u : (u | 0x80000000u);
}
__device__ __forceinline__ float dec_key(unsigned k) {
    unsigned u = (k & 0x80000000u) ? (k ^ 0x80000000u) : ~k;
    return __builtin_bit_cast(float, u);
}

// ---------------- workspace layout (bytes), ~39 MiB ----------------
#define WS_XPT   0                                   // bf16 [H][64][N]
#define WS_U     (WS_XPT + HH * FD * NN * 2)         // f32  [H][N]  s_self
#define WS_V     (WS_U + HH * NN * 4)                // f32  [H][N]  s_neigh
#define WS_MK    (WS_V + HH * NN * 4)                // u32  [8]: maxU keys [0..3], maxV keys [4..7]
#define WS_WT    (WS_MK + 256)                       // bf16 [H][64][128]
#define WS_ACCP  (WS_WT + HH * FD * FF * 2)          // bf16 [SPLIT][H][N][64]
#define WS_LP    (WS_ACCP + (size_t)SPLIT * HH * NN * FD * 2)  // f32 [SPLIT][H][N]

// ---------------- K0: W transpose + zero max-keys ----------------
__global__ void k0_transpose_w(const float* __restrict__ W,
                               unsigned short* __restrict__ WT,
                               unsigned* __restrict__ MK) {
    int b = blockIdx.x;            // 32 blocks
    int t = threadIdx.x;
    if (b == 0 && t < 8) MK[t] = 0u;   // key 0 == most-negative float
    int h = b >> 3, fb = b & 7;
    int d = t & 63, fo = t >> 6;
    #pragma unroll
    for (int i = 0; i < 4; ++i) {
        int f = fb * 16 + fo * 4 + i;
        WT[(h * FD + d) * FF + f] = (unsigned short)f32_to_bf16_rne(W[(h * FF + f) * FD + d]);
    }
}

// ---------------- K1: Xp = X @ W[h]; scores; XpT bf16; head max via atomics ----
__global__ __launch_bounds__(256) void k1_project(
        const float* __restrict__ X,               // [N][128] f32
        const unsigned short* __restrict__ WT,     // [H][64][128] bf16
        const float* __restrict__ a_self,          // [H][64] f32
        const float* __restrict__ a_neigh,
        unsigned short* __restrict__ XpT,          // [H][64][N] bf16
        float* __restrict__ U, float* __restrict__ V,
        unsigned* __restrict__ MK) {
    __shared__ __align__(16) char XsB[64 * 272];
    __shared__ __align__(16) char WsB[64 * 272];
    const int rb = blockIdx.x * 64;
    const int h  = blockIdx.y;
    const int t  = threadIdx.x;
    const float4* xs = (const float4*)(X + (size_t)rb * FF);
    #pragma unroll
    for (int i = 0; i < 8; ++i) {
        int c = i * 256 + t;
        float4 v = xs[c];
        uint2 pv;
        pv.x = f32_to_bf16_rne(v.x) | (f32_to_bf16_rne(v.y) << 16);
        pv.y = f32_to_bf16_rne(v.z) | (f32_to_bf16_rne(v.w) << 16);
        *(uint2*)(XsB + (c >> 5) * 272 + (c & 31) * 8) = pv;
    }
    const uint4* wsrc = (const uint4*)(WT + (size_t)h * FD * FF);
    #pragma unroll
    for (int i = 0; i < 4; ++i) {
        int c = i * 256 + t;
        *(uint4*)(WsB + (c >> 4) * 272 + (c & 15) * 16) = wsrc[c];
    }
    __syncthreads();
    const int lane = t & 63, wid = t >> 6;
    const int r15 = lane & 15, quad = lane >> 4;
    const int lrow = wid * 16 + r15;

    f32x4 acc[4];
    #pragma unroll
    for (int cg = 0; cg < 4; ++cg) acc[cg] = (f32x4){0.f, 0.f, 0.f, 0.f};
    #pragma unroll
    for (int kt = 0; kt < 4; ++kt) {
        short8 afr = *(const short8*)(XsB + lrow * 272 + kt * 64 + quad * 16);
        #pragma unroll
        for (int cg = 0; cg < 4; ++cg) {
            short8 bfr = *(const short8*)(WsB + (cg * 16 + r15) * 272 + kt * 64 + quad * 16);
            acc[cg] = __builtin_amdgcn_mfma_f32_16x16x32_bf16(afr, bfr, acc[cg], 0, 0, 0);
        }
    }
    float as[4], an[4];
    #pragma unroll
    for (int cg = 0; cg < 4; ++cg) {
        as[cg] = a_self[h * FD + cg * 16 + r15];
        an[cg] = a_neigh[h * FD + cg * 16 + r15];
    }
    float mu = -1e30f, mv = -1e30f;
    #pragma unroll
    for (int reg = 0; reg < 4; ++reg) {
        float s1 = 0.f, s2 = 0.f;
        #pragma unroll
        for (int cg = 0; cg < 4; ++cg) { s1 += acc[cg][reg] * as[cg]; s2 += acc[cg][reg] * an[cg]; }
        #pragma unroll
        for (int m = 1; m <= 8; m <<= 1) { s1 += __shfl_xor(s1, m); s2 += __shfl_xor(s2, m); }
        mu = fmaxf(mu, s1); mv = fmaxf(mv, s2);
        if (r15 == 0) {
            int n = rb + wid * 16 + quad * 4 + reg;
            U[h * NN + n] = s1;
            V[h * NN + n] = s2;
        }
    }
    mu = fmaxf(mu, __shfl_xor(mu, 16)); mu = fmaxf(mu, __shfl_xor(mu, 32));
    mv = fmaxf(mv, __shfl_xor(mv, 16)); mv = fmaxf(mv, __shfl_xor(mv, 32));
    if (lane == 0) {
        atomicMax(&MK[h], enc_key(mu));
        atomicMax(&MK[4 + h], enc_key(mv));
    }
    #pragma unroll
    for (int cg = 0; cg < 4; ++cg) {
        uint2 val;
        val.x = f32_to_bf16_rne(acc[cg][0]) | (f32_to_bf16_rne(acc[cg][1]) << 16);
        val.y = f32_to_bf16_rne(acc[cg][2]) | (f32_to_bf16_rne(acc[cg][3]) << 16);
        int d = cg * 16 + r15;
        int n0 = rb + wid * 16 + quad * 4;
        *(uint2*)((char*)XpT + ((size_t)(h * FD + d) * NN + n0) * 2) = val;
    }
}

// ---------------- K2: fused scores/softmax-numerator + P.V MFMA ----------------
// 4 waves = 64 rows; wave w owns head w; grid (128 row-blocks, SPLIT m-splits).
// Both XpT and A tiles staged via async global_load_lds, double-buffered.
// XpT swizzle (verified 0-conflict r3): LDS(row,c') = global chunk c' ^ ((row>>1)&3).
// A swizzle on chunk bits 2:1 only (keeps 32B pair order): c' = c ^ (((row>>1)&3)<<1).
__global__ __launch_bounds__(256, 3) void k2_attend(
        const float* __restrict__ Ag,              // [N][N] f32 0/1
        const unsigned short* __restrict__ XpT,    // [H][64][N] bf16
        const float* __restrict__ U, const float* __restrict__ V,
        const unsigned* __restrict__ MK,
        unsigned short* __restrict__ accP,         // [SPLIT][H][N][64] bf16
        float* __restrict__ lP) {                  // f32 [SPLIT][H][N]
    __shared__ __align__(16) char Xsb[2][16384];   // 2 x (256 rows x 64B)
    __shared__ __align__(16) char Asb[2][8192];    // 2 x (64 rows x 128B)
    const int t = threadIdx.x;
    const int lane = t & 63, wid = t >> 6;
    const int r15 = lane & 15, quad = lane >> 4;
    const int rb = blockIdx.x * 64;
    const int sp = blockIdx.y;
    const int h = wid;                             // head-per-wave
    const int kb0 = sp * (NN / SPLIT);

    const float M = dec_key(MK[h]) + dec_key(MK[4 + h]);
    const float qoff = -0.8f * M * LOG2E;          // q = 0.2*p + qoff == (0.2 s - M)*log2e
    float u1g[4];
    #pragma unroll
    for (int g = 0; g < 4; ++g)
        u1g[g] = (U[h * NN + rb + g * 16 + r15] - M) * LOG2E;

    f32x4 acc[4][4];
    #pragma unroll
    for (int g = 0; g < 4; ++g)
        #pragma unroll
        for (int cg = 0; cg < 4; ++cg) acc[g][cg] = (f32x4){0.f, 0.f, 0.f, 0.f};
    float lsum[4] = {0.f, 0.f, 0.f, 0.f};

    // XpT DMA source: instr i covers LDS rows wid*64+i*16 .. +15 (4 lanes/row)
    const int srX = wid * 64 + (lane >> 2);
    const int scX = (lane & 3) ^ ((lane >> 3) & 3);
    const char* xsrc = (const char*)XpT + ((size_t)srX * NN + kb0 + scX * 8) * 2;
    const size_t xstep = (size_t)16 * NN * 2;      // +16 source rows per instr
    // A DMA source: instr i covers tile rows wid*16+i*8 .. +7 (8 lanes/row)
    const int rA = wid * 16 + (lane >> 3);
    const int chA = (lane & 7) ^ (((rA >> 1) & 3) << 1);
    const float* asrc = Ag + (size_t)(rb + rA) * NN + kb0 + chA * 4;
    const size_t astep = (size_t)8 * NN;           // +8 source rows per instr (floats)

    // issue tile 0 into buffer 0
    #pragma unroll
    for (int i = 0; i < 4; ++i)
        async_load16(xsrc + (size_t)i * xstep, &Xsb[0][(wid * 4 + i) * 1024]);
    #pragma unroll
    for (int i = 0; i < 2; ++i)
        async_load16(asrc + i * astep, &Asb[0][(wid * 2 + i) * 1024]);

    // V (s_neigh) register prefetch: 8 floats/lane/tile, L2-hot
    const float* vbase = V + h * NN + kb0 + quad * 8;
    float4 vg[2][2];
    vg[0][0] = *(const float4*)(vbase);
    vg[0][1] = *(const float4*)(vbase + 4);

    const int swzX = (quad ^ ((r15 >> 1) & 3)) * 16;   // XpT read chunk offset (bytes)
    const int swzA = (quad ^ ((r15 >> 1) & 3)) * 32;   // A read 32B-pair offset (bytes)

    #pragma unroll 2
    for (int kt = 0; kt < KT_PER_SPLIT; ++kt) {
        const int cur = kt & 1, nxt = cur ^ 1;
        __syncthreads();                           // drains tile-kt DMA into buf[cur]
        if (kt + 1 < KT_PER_SPLIT) {               // prefetch tile kt+1 -> buf[nxt]
            const char*  xs2 = xsrc + (size_t)(kt + 1) * 64;   // 32 bf16 cols
            const float* as2 = asrc + (size_t)(kt + 1) * 32;   // 32 f32 cols
            #pragma unroll
            for (int i = 0; i < 4; ++i)
                async_load16(xs2 + (size_t)i * xstep, &Xsb[nxt][(wid * 4 + i) * 1024]);
            #pragma unroll
            for (int i = 0; i < 2; ++i)
                async_load16(as2 + i * astep, &Asb[nxt][(wid * 2 + i) * 1024]);
        }
        {   // V prefetch for next tile (clamped duplicate on last iter)
            const int ktn = (kt + 1 < KT_PER_SPLIT) ? kt + 1 : kt;
            vg[nxt][0] = *(const float4*)(vbase + ktn * 32);
            vg[nxt][1] = *(const float4*)(vbase + ktn * 32 + 4);
        }
        // B-frags for head h (shared across g)
        short8 bfr[4];
        #pragma unroll
        for (int cg = 0; cg < 4; ++cg)
            bfr[cg] = *(const short8*)(&Xsb[cur][(h * FD + cg * 16 + r15) * 64 + swzX]);

        #pragma unroll
        for (int g = 0; g < 4; ++g) {
            const char* arow = &Asb[cur][(g * 16 + r15) * 128 + swzA];
            f32x4 a0 = *(const f32x4*)(arow);          // mask cols quad*8..+3
            f32x4 a1 = *(const f32x4*)(arow + 16);     // mask cols quad*8+4..+7
            float w[8];
            #pragma unroll
            for (int j = 0; j < 4; ++j) {
                float p = fmaf(((const float*)&vg[cur][0])[j], LOG2E, u1g[g]);
                float q = fmaf(0.2f, p, qoff);
                w[j] = fast_exp2(fmaxf(p, q)) * a0[j];
            }
            #pragma unroll
            for (int j = 0; j < 4; ++j) {
                float p = fmaf(((const float*)&vg[cur][1])[j], LOG2E, u1g[g]);
                float q = fmaf(0.2f, p, qoff);
                w[4 + j] = fast_exp2(fmaxf(p, q)) * a1[j];
            }
            lsum[g] += ((w[0] + w[1]) + (w[2] + w[3])) + ((w[4] + w[5]) + (w[6] + w[7]));
            uint4 pkv;
            pkv.x = pack_bf16_trunc(w[0], w[1]);
            pkv.y = pack_bf16_trunc(w[2], w[3]);
            pkv.z = pack_bf16_trunc(w[4], w[5]);
            pkv.w = pack_bf16_trunc(w[6], w[7]);
            short8 afrag = __builtin_bit_cast(short8, pkv);
            #pragma unroll
            for (int cg = 0; cg < 4; ++cg)
                acc[g][cg] = __builtin_amdgcn_mfma_f32_16x16x32_bf16(afrag, bfr[cg], acc[g][cg], 0, 0, 0);
        }
    }
    // row denominators: combine the 4 quad-lanes sharing each row
    #pragma unroll
    for (int g = 0; g < 4; ++g) {
        lsum[g] += __shfl_xor(lsum[g], 16);
        lsum[g] += __shfl_xor(lsum[g], 32);
    }
    if (lane < 16) {
        #pragma unroll
        for (int g = 0; g < 4; ++g)
            lP[(size_t)(sp * HH + h) * NN + rb + g * 16 + lane] = lsum[g];
    }
    #pragma unroll
    for (int g = 0; g < 4; ++g)
        #pragma unroll
        for (int cg = 0; cg < 4; ++cg) {
            int d = cg * 16 + r15;
            #pragma unroll
            for (int reg = 0; reg < 4; ++reg) {
                int n = rb + g * 16 + quad * 4 + reg;
                accP[((size_t)(sp * HH + h) * NN + n) * FD + d] =
                    (unsigned short)f32_to_bf16_rne(acc[g][cg][reg]);
            }
        }
}

// ---------------- K3: combine splits, divide, relu, concat ----------------
__global__ void k3_combine(const unsigned short* __restrict__ accP,
                           const float* __restrict__ lP,
                           float* __restrict__ out) {
    int e = blockIdx.x * 256 + threadIdx.x;     // 2M elements: out[n][h*64+d]
    int n = e >> 8, c = e & 255;
    int h = c >> 6, d = c & 63;
    float num = 0.f, den = 0.f;
    #pragma unroll
    for (int s = 0; s < SPLIT; ++s) {
        num += bf16_to_f32(accP[((size_t)(s * HH + h) * NN + n) * FD + d]);
        den += lP[(size_t)(s * HH + h) * NN + n];
    }
    out[e] = fmaxf(num * __builtin_amdgcn_rcpf(den), 0.f);
}

extern "C" void kernel_launch(void* const* d_in, const int* in_sizes, int n_in,
                              void* d_out, int out_size, void* d_ws, size_t ws_size,
                              hipStream_t stream) {
    (void)in_sizes; (void)n_in; (void)out_size; (void)ws_size;
    const float* X       = (const float*)d_in[0];
    const float* A       = (const float*)d_in[1];
    const float* W       = (const float*)d_in[2];
    const float* a_self  = (const float*)d_in[3];
    const float* a_neigh = (const float*)d_in[4];
    char* ws = (char*)d_ws;
    unsigned short* XpT  = (unsigned short*)(ws + WS_XPT);
    float*          U    = (float*)(ws + WS_U);
    float*          V    = (float*)(ws + WS_V);
    unsigned*       MK   = (unsigned*)(ws + WS_MK);
    unsigned short* WT   = (unsigned short*)(ws + WS_WT);
    unsigned short* accP = (unsigned short*)(ws + WS_ACCP);
    float*          lP   = (float*)(ws + WS_LP);
    float*          out  = (float*)d_out;

    k0_transpose_w<<<dim3(32), dim3(256), 0, stream>>>(W, WT, MK);
    k1_project<<<dim3(NN / 64, HH), dim3(256), 0, stream>>>(X, WT, a_self, a_neigh, XpT, U, V, MK);
    k2_attend<<<dim3(NN / 64, SPLIT), dim3(256), 0, stream>>>(A, XpT, U, V, MK, accP, lP);
    k3_combine<<<dim3(NN), dim3(256), 0, stream>>>(accP, lP, out);
}

// Round 5
// 495.459 us; speedup vs baseline: 1.3839x; 1.0216x over previous
//
#include <hip/hip_runtime.h>
#include <stdint.h>

// GraphAttention on MI355X — ALL I/O float32.
// X[8192][128], A[8192][8192] (0/1), W[4][128][64], a_self[4][64], a_neigh[4][64]
// -> out f32 [8192][256].
//
// K0 W->WT bf16 + zero max-keys -> K1 MFMA projection + scores + atomicMax head
// bounds -> K2 fused mask/exp/softmax-num + P.V MFMA (all global traffic via
// global_load_lds double-buffer; head-per-wave; 128-row blocks; m-split=8)
// -> K3 combine/divide/relu.

#define NN    8192
#define FF    128
#define FD    64
#define HH    4
#define SPLIT 8
#define RB    128                          // rows per block in K2
#define NG    (RB / 16)                    // 8 MFMA row-groups per wave
#define KT_PER_SPLIT ((NN / SPLIT) / 32)   // 32 k-tiles of 32 columns per split
#define LOG2E 1.4426950408889634f

typedef __attribute__((ext_vector_type(8))) short short8;
typedef __attribute__((ext_vector_type(4))) float f32x4;

extern "C" __device__ float __ocml_exp2_f32(float);

__device__ __forceinline__ float fast_exp2(float x) {
#if __has_builtin(__builtin_amdgcn_exp2f)
    return __builtin_amdgcn_exp2f(x);
#else
    return __ocml_exp2_f32(x);
#endif
}

__device__ __forceinline__ float bf16_to_f32(unsigned short u) {
    return __builtin_bit_cast(float, ((unsigned)u) << 16);
}
__device__ __forceinline__ unsigned f32_to_bf16_rne(float f) {
    unsigned u = __builtin_bit_cast(unsigned, f);
    u = (u + 0x7FFFu + ((u >> 16) & 1u)) >> 16;
    return u;
}
// Pack two f32 -> two bf16 (truncation) in ONE v_perm_b32.  lo -> bits[15:0].
__device__ __forceinline__ unsigned pack_bf16_trunc(float lo, float hi) {
    return __builtin_amdgcn_perm(__builtin_bit_cast(unsigned, hi),
                                 __builtin_bit_cast(unsigned, lo), 0x07060302u);
}
// async global->LDS DMA, 16B per lane; LDS dest = ldsbase + lane*16.
__device__ __forceinline__ void async_load16(const void* g, void* l) {
    __builtin_amdgcn_global_load_lds(
        (const __attribute__((address_space(1))) unsigned int*)g,
        (__attribute__((address_space(3))) unsigned int*)l, 16, 0, 0);
}
// order-preserving float<->uint keys for atomicMax over signed floats
__device__ __forceinline__ unsigned enc_key(float f) {
    unsigned u = __builtin_bit_cast(unsigned, f);
    return (u & 0x80000000u) ? ~u : (u | 0x80000000u);
}
__device__ __forceinline__ float dec_key(unsigned k) {
    unsigned u = (k & 0x80000000u) ? (k ^ 0x80000000u) : ~k;
    return __builtin_bit_cast(float, u);
}

// ---------------- workspace layout (bytes), ~39 MiB ----------------
#define WS_XPT   0                                   // bf16 [H][64][N]
#define WS_U     (WS_XPT + HH * FD * NN * 2)         // f32  [H][N]  s_self
#define WS_V     (WS_U + HH * NN * 4)                // f32  [H][N]  s_neigh
#define WS_MK    (WS_V + HH * NN * 4)                // u32  [8]: maxU keys, maxV keys
#define WS_WT    (WS_MK + 256)                       // bf16 [H][64][128]
#define WS_ACCP  (WS_WT + HH * FD * FF * 2)          // bf16 [SPLIT][H][N][64]
#define WS_LP    (WS_ACCP + (size_t)SPLIT * HH * NN * FD * 2)  // f32 [SPLIT][H][N]

// ---------------- K0: W transpose + zero max-keys ----------------
__global__ void k0_transpose_w(const float* __restrict__ W,
                               unsigned short* __restrict__ WT,
                               unsigned* __restrict__ MK) {
    int b = blockIdx.x;            // 32 blocks
    int t = threadIdx.x;
    if (b == 0 && t < 8) MK[t] = 0u;   // key 0 == most-negative float
    int h = b >> 3, fb = b & 7;
    int d = t & 63, fo = t >> 6;
    #pragma unroll
    for (int i = 0; i < 4; ++i) {
        int f = fb * 16 + fo * 4 + i;
        WT[(h * FD + d) * FF + f] = (unsigned short)f32_to_bf16_rne(W[(h * FF + f) * FD + d]);
    }
}

// ---------------- K1: Xp = X @ W[h]; scores; XpT bf16; head max via atomics ----
__global__ __launch_bounds__(256) void k1_project(
        const float* __restrict__ X,               // [N][128] f32
        const unsigned short* __restrict__ WT,     // [H][64][128] bf16
        const float* __restrict__ a_self,          // [H][64] f32
        const float* __restrict__ a_neigh,
        unsigned short* __restrict__ XpT,          // [H][64][N] bf16
        float* __restrict__ U, float* __restrict__ V,
        unsigned* __restrict__ MK) {
    __shared__ __align__(16) char XsB[64 * 272];
    __shared__ __align__(16) char WsB[64 * 272];
    const int rb = blockIdx.x * 64;
    const int h  = blockIdx.y;
    const int t  = threadIdx.x;
    const float4* xs = (const float4*)(X + (size_t)rb * FF);
    #pragma unroll
    for (int i = 0; i < 8; ++i) {
        int c = i * 256 + t;
        float4 v = xs[c];
        uint2 pv;
        pv.x = f32_to_bf16_rne(v.x) | (f32_to_bf16_rne(v.y) << 16);
        pv.y = f32_to_bf16_rne(v.z) | (f32_to_bf16_rne(v.w) << 16);
        *(uint2*)(XsB + (c >> 5) * 272 + (c & 31) * 8) = pv;
    }
    const uint4* wsrc = (const uint4*)(WT + (size_t)h * FD * FF);
    #pragma unroll
    for (int i = 0; i < 4; ++i) {
        int c = i * 256 + t;
        *(uint4*)(WsB + (c >> 4) * 272 + (c & 15) * 16) = wsrc[c];
    }
    __syncthreads();
    const int lane = t & 63, wid = t >> 6;
    const int r15 = lane & 15, quad = lane >> 4;
    const int lrow = wid * 16 + r15;

    f32x4 acc[4];
    #pragma unroll
    for (int cg = 0; cg < 4; ++cg) acc[cg] = (f32x4){0.f, 0.f, 0.f, 0.f};
    #pragma unroll
    for (int kt = 0; kt < 4; ++kt) {
        short8 afr = *(const short8*)(XsB + lrow * 272 + kt * 64 + quad * 16);
        #pragma unroll
        for (int cg = 0; cg < 4; ++cg) {
            short8 bfr = *(const short8*)(WsB + (cg * 16 + r15) * 272 + kt * 64 + quad * 16);
            acc[cg] = __builtin_amdgcn_mfma_f32_16x16x32_bf16(afr, bfr, acc[cg], 0, 0, 0);
        }
    }
    float as[4], an[4];
    #pragma unroll
    for (int cg = 0; cg < 4; ++cg) {
        as[cg] = a_self[h * FD + cg * 16 + r15];
        an[cg] = a_neigh[h * FD + cg * 16 + r15];
    }
    float mu = -1e30f, mv = -1e30f;
    #pragma unroll
    for (int reg = 0; reg < 4; ++reg) {
        float s1 = 0.f, s2 = 0.f;
        #pragma unroll
        for (int cg = 0; cg < 4; ++cg) { s1 += acc[cg][reg] * as[cg]; s2 += acc[cg][reg] * an[cg]; }
        #pragma unroll
        for (int m = 1; m <= 8; m <<= 1) { s1 += __shfl_xor(s1, m); s2 += __shfl_xor(s2, m); }
        mu = fmaxf(mu, s1); mv = fmaxf(mv, s2);
        if (r15 == 0) {
            int n = rb + wid * 16 + quad * 4 + reg;
            U[h * NN + n] = s1;
            V[h * NN + n] = s2;
        }
    }
    mu = fmaxf(mu, __shfl_xor(mu, 16)); mu = fmaxf(mu, __shfl_xor(mu, 32));
    mv = fmaxf(mv, __shfl_xor(mv, 16)); mv = fmaxf(mv, __shfl_xor(mv, 32));
    if (lane == 0) {
        atomicMax(&MK[h], enc_key(mu));
        atomicMax(&MK[4 + h], enc_key(mv));
    }
    #pragma unroll
    for (int cg = 0; cg < 4; ++cg) {
        uint2 val;
        val.x = f32_to_bf16_rne(acc[cg][0]) | (f32_to_bf16_rne(acc[cg][1]) << 16);
        val.y = f32_to_bf16_rne(acc[cg][2]) | (f32_to_bf16_rne(acc[cg][3]) << 16);
        int d = cg * 16 + r15;
        int n0 = rb + wid * 16 + quad * 4;
        *(uint2*)((char*)XpT + ((size_t)(h * FD + d) * NN + n0) * 2) = val;
    }
}

// ---------------- K2: fused scores/softmax-numerator + P.V MFMA ----------------
// 4 waves; wave w owns head w, processes all 128 block rows (NG=8 row-groups).
// grid (64 row-blocks, SPLIT m-splits) = 512 blocks = 2/CU.
// XpT staged per wave (own head rows), swizzle: LDS chunk c' = c ^ ((row>>1)&3)
//   (0 LDS conflicts, verified round 3/4).
// A staged 128x32 f32; slot(row, idx) = row*8 + (idx ^ (row&7)) 16B chunks
//   -> mask reads are 2-way (free).  DMA source perm is lane-constant.
__global__ __launch_bounds__(256, 2) void k2_attend(
        const float* __restrict__ Ag,              // [N][N] f32 0/1
        const unsigned short* __restrict__ XpT,    // [H][64][N] bf16
        const float* __restrict__ U, const float* __restrict__ V,
        const unsigned* __restrict__ MK,
        unsigned short* __restrict__ accP,         // [SPLIT][H][N][64] bf16
        float* __restrict__ lP) {                  // f32 [SPLIT][H][N]
    __shared__ __align__(16) char Xsb[2][16384];   // 2 x (256 rows x 64B)
    __shared__ __align__(16) char Asb[2][16384];   // 2 x (128 rows x 128B)
    const int t = threadIdx.x;
    const int lane = t & 63, wid = t >> 6;
    const int r15 = lane & 15, quad = lane >> 4;
    const int rb = blockIdx.x * RB;
    const int sp = blockIdx.y;
    const int h = wid;                             // head-per-wave
    const int kb0 = sp * (NN / SPLIT);

    const float M = dec_key(MK[h]) + dec_key(MK[4 + h]);
    const float qoff = -0.8f * M * LOG2E;          // q = 0.2*p + qoff == (0.2 s - M)*log2e
    float u1g[NG];
    #pragma unroll
    for (int g = 0; g < NG; ++g)
        u1g[g] = (U[h * NN + rb + g * 16 + r15] - M) * LOG2E;

    f32x4 acc[NG][4];
    #pragma unroll
    for (int g = 0; g < NG; ++g)
        #pragma unroll
        for (int cg = 0; cg < 4; ++cg) acc[g][cg] = (f32x4){0.f, 0.f, 0.f, 0.f};
    float lsum[NG];
    #pragma unroll
    for (int g = 0; g < NG; ++g) lsum[g] = 0.f;

    // XpT DMA: wave w stages head-w rows; instr i covers LDS rows w*64+i*16..+15
    const int srX = wid * 64 + (lane >> 2);
    const int scX = (lane & 3) ^ ((lane >> 3) & 3);
    const char* xsrc = (const char*)XpT + ((size_t)srX * NN + kb0 + scX * 8) * 2;
    const size_t xstep = (size_t)16 * NN * 2;      // +16 source rows per instr
    // A DMA: instr i covers tile rows wid*32+i*8..+7 (8 lanes/row, 16B chunks)
    const int rA = wid * 32 + (lane >> 3);
    const int chA = (lane & 7) ^ ((lane >> 3) & 7);    // idx = slot ^ (row&7)
    const float* asrc = Ag + (size_t)(rb + rA) * NN + kb0 + chA * 4;
    const size_t astep = (size_t)8 * NN;           // +8 source rows per instr

    // issue tile 0 into buffer 0
    #pragma unroll
    for (int i = 0; i < 4; ++i)
        async_load16(xsrc + (size_t)i * xstep, &Xsb[0][(wid * 4 + i) * 1024]);
    #pragma unroll
    for (int i = 0; i < 4; ++i)
        async_load16(asrc + (size_t)i * astep, &Asb[0][(wid * 4 + i) * 1024]);

    // V (s_neigh) register prefetch: 8 floats/lane/tile, L2-hot
    const float* vbase = V + h * NN + kb0 + quad * 8;
    float4 vg[2][2];
    vg[0][0] = *(const float4*)(vbase);
    vg[0][1] = *(const float4*)(vbase + 4);

    const int swzX  = (quad ^ ((r15 >> 1) & 3)) * 16;      // XpT read chunk offset
    const int swzA0 = ((2 * quad) ^ (r15 & 7)) * 16;       // A chunk idx 2q slot
    const int swzA1 = ((2 * quad + 1) ^ (r15 & 7)) * 16;   // A chunk idx 2q+1 slot

    #pragma unroll 2
    for (int kt = 0; kt < KT_PER_SPLIT; ++kt) {
        const int cur = kt & 1, nxt = cur ^ 1;
        __syncthreads();                           // drains tile-kt DMA into buf[cur]
        if (kt + 1 < KT_PER_SPLIT) {               // prefetch tile kt+1 -> buf[nxt]
            const char*  xs2 = xsrc + (size_t)(kt + 1) * 64;   // 32 bf16 cols
            const float* as2 = asrc + (size_t)(kt + 1) * 32;   // 32 f32 cols
            #pragma unroll
            for (int i = 0; i < 4; ++i)
                async_load16(xs2 + (size_t)i * xstep, &Xsb[nxt][(wid * 4 + i) * 1024]);
            #pragma unroll
            for (int i = 0; i < 4; ++i)
                async_load16(as2 + (size_t)i * astep, &Asb[nxt][(wid * 4 + i) * 1024]);
        }
        {   // V prefetch for next tile (clamped duplicate on last iter)
            const int ktn = (kt + 1 < KT_PER_SPLIT) ? kt + 1 : kt;
            vg[nxt][0] = *(const float4*)(vbase + ktn * 32);
            vg[nxt][1] = *(const float4*)(vbase + ktn * 32 + 4);
        }
        // B-frags for head h (shared across all row-groups)
        short8 bfr[4];
        #pragma unroll
        for (int cg = 0; cg < 4; ++cg)
            bfr[cg] = *(const short8*)(&Xsb[cur][(h * FD + cg * 16 + r15) * 64 + swzX]);

        #pragma unroll
        for (int g = 0; g < NG; ++g) {
            const char* arow = &Asb[cur][(g * 16 + r15) * 128];
            f32x4 a0 = *(const f32x4*)(arow + swzA0);  // mask cols quad*8..+3
            f32x4 a1 = *(const f32x4*)(arow + swzA1);  // mask cols quad*8+4..+7
            float w[8];
            #pragma unroll
            for (int j = 0; j < 4; ++j) {
                float p = fmaf(((const float*)&vg[cur][0])[j], LOG2E, u1g[g]);
                float q = fmaf(0.2f, p, qoff);
                w[j] = fast_exp2(fmaxf(p, q)) * a0[j];
            }
            #pragma unroll
            for (int j = 0; j < 4; ++j) {
                float p = fmaf(((const float*)&vg[cur][1])[j], LOG2E, u1g[g]);
                float q = fmaf(0.2f, p, qoff);
                w[4 + j] = fast_exp2(fmaxf(p, q)) * a1[j];
            }
            lsum[g] += ((w[0] + w[1]) + (w[2] + w[3])) + ((w[4] + w[5]) + (w[6] + w[7]));
            uint4 pkv;
            pkv.x = pack_bf16_trunc(w[0], w[1]);
            pkv.y = pack_bf16_trunc(w[2], w[3]);
            pkv.z = pack_bf16_trunc(w[4], w[5]);
            pkv.w = pack_bf16_trunc(w[6], w[7]);
            short8 afrag = __builtin_bit_cast(short8, pkv);
            #pragma unroll
            for (int cg = 0; cg < 4; ++cg)
                acc[g][cg] = __builtin_amdgcn_mfma_f32_16x16x32_bf16(afrag, bfr[cg], acc[g][cg], 0, 0, 0);
        }
    }
    // row denominators: combine the 4 quad-lanes sharing each row
    #pragma unroll
    for (int g = 0; g < NG; ++g) {
        lsum[g] += __shfl_xor(lsum[g], 16);
        lsum[g] += __shfl_xor(lsum[g], 32);
    }
    if (lane < 16) {
        #pragma unroll
        for (int g = 0; g < NG; ++g)
            lP[(size_t)(sp * HH + h) * NN + rb + g * 16 + lane] = lsum[g];
    }
    #pragma unroll
    for (int g = 0; g < NG; ++g)
        #pragma unroll
        for (int cg = 0; cg < 4; ++cg) {
            int d = cg * 16 + r15;
            #pragma unroll
            for (int reg = 0; reg < 4; ++reg) {
                int n = rb + g * 16 + quad * 4 + reg;
                accP[((size_t)(sp * HH + h) * NN + n) * FD + d] =
                    (unsigned short)f32_to_bf16_rne(acc[g][cg][reg]);
            }
        }
}

// ---------------- K3: combine splits, divide, relu, concat ----------------
__global__ void k3_combine(const unsigned short* __restrict__ accP,
                           const float* __restrict__ lP,
                           float* __restrict__ out) {
    int e = blockIdx.x * 256 + threadIdx.x;     // 2M elements: out[n][h*64+d]
    int n = e >> 8, c = e & 255;
    int h = c >> 6, d = c & 63;
    float num = 0.f, den = 0.f;
    #pragma unroll
    for (int s = 0; s < SPLIT; ++s) {
        num += bf16_to_f32(accP[((size_t)(s * HH + h) * NN + n) * FD + d]);
        den += lP[(size_t)(s * HH + h) * NN + n];
    }
    out[e] = fmaxf(num * __builtin_amdgcn_rcpf(den), 0.f);
}

extern "C" void kernel_launch(void* const* d_in, const int* in_sizes, int n_in,
                              void* d_out, int out_size, void* d_ws, size_t ws_size,
                              hipStream_t stream) {
    (void)in_sizes; (void)n_in; (void)out_size; (void)ws_size;
    const float* X       = (const float*)d_in[0];
    const float* A       = (const float*)d_in[1];
    const float* W       = (const float*)d_in[2];
    const float* a_self  = (const float*)d_in[3];
    const float* a_neigh = (const float*)d_in[4];
    char* ws = (char*)d_ws;
    unsigned short* XpT  = (unsigned short*)(ws + WS_XPT);
    float*          U    = (float*)(ws + WS_U);
    float*          V    = (float*)(ws + WS_V);
    unsigned*       MK   = (unsigned*)(ws + WS_MK);
    unsigned short* WT   = (unsigned short*)(ws + WS_WT);
    unsigned short* accP = (unsigned short*)(ws + WS_ACCP);
    float*          lP   = (float*)(ws + WS_LP);
    float*          out  = (float*)d_out;

    k0_transpose_w<<<dim3(32), dim3(256), 0, stream>>>(W, WT, MK);
    k1_project<<<dim3(NN / 64, HH), dim3(256), 0, stream>>>(X, WT, a_self, a_neigh, XpT, U, V, MK);
    k2_attend<<<dim3(NN / RB, SPLIT), dim3(256), 0, stream>>>(A, XpT, U, V, MK, accP, lP);
    k3_combine<<<dim3(NN), dim3(256), 0, stream>>>(accP, lP, out);
}